// Round 1
// baseline (2108.933 us; speedup 1.0000x reference)
//
#include <hip/hip_runtime.h>
#include <math.h>

#define BB 32
#define S_PAST 4095
#define S_TOT 4096
#define HH 2048
#define NHEAD 16
#define HD 128
#define N_QKV 6144
#define KSPLIT 8
#define KCHUNK 256       // 2048 / KSPLIT
#define NCHUNK 4
#define SCHUNK 1024      // 4096 / NCHUNK
#define PART_STRIDE 132  // 128 ctx + m + l, padded to 4

// ---------------- skinny GEMM: P[ks][b][col] = sum_{k in chunk} X[b][k]*W[k][col]
__global__ __launch_bounds__(256) void gemm_xw_partial(
    const float* __restrict__ X,   // [BB][2048]
    const float* __restrict__ W,   // [2048][N]
    float* __restrict__ P,         // [KSPLIT][BB][N]
    int N)
{
    __shared__ __align__(16) float4 xs4[BB][KCHUNK / 4];  // 32 KB
    const int tid = threadIdx.x;
    const int cb  = blockIdx.x;
    const int ks  = blockIdx.y;

    const float4* Xf4 = (const float4*)X;
    #pragma unroll
    for (int i = 0; i < 8; ++i) {
        int flat = tid + i * 256;          // 0..2047
        int b    = flat >> 6;
        int kk4  = flat & 63;
        xs4[b][kk4] = Xf4[b * 512 + ks * 64 + kk4];
    }
    __syncthreads();

    const int col = cb * 256 + tid;
    float acc[BB];
    #pragma unroll
    for (int b = 0; b < BB; ++b) acc[b] = 0.f;

    const float* wp = W + (size_t)(ks * KCHUNK) * N + col;
    for (int kk4 = 0; kk4 < KCHUNK / 4; ++kk4) {
        float w0 = wp[0];
        float w1 = wp[(size_t)N];
        float w2 = wp[(size_t)2 * N];
        float w3 = wp[(size_t)3 * N];
        wp += (size_t)4 * N;
        #pragma unroll
        for (int b = 0; b < BB; ++b) {
            float4 xv = xs4[b][kk4];
            acc[b] = fmaf(xv.x, w0, acc[b]);
            acc[b] = fmaf(xv.y, w1, acc[b]);
            acc[b] = fmaf(xv.z, w2, acc[b]);
            acc[b] = fmaf(xv.w, w3, acc[b]);
        }
    }
    float* pp = P + (size_t)ks * BB * N + col;
    #pragma unroll
    for (int b = 0; b < BB; ++b) pp[(size_t)b * N] = acc[b];
}

// ---------------- reduce split-K partials + bias
__global__ __launch_bounds__(256) void reduce_bias(
    const float* __restrict__ P, const float* __restrict__ bias,
    float* __restrict__ Y, int N)
{
    int idx = blockIdx.x * 256 + threadIdx.x;   // over BB*N
    float s = 0.f;
    #pragma unroll
    for (int ks = 0; ks < KSPLIT; ++ks) s += P[(size_t)ks * BB * N + idx];
    int col = idx % N;
    Y[idx] = s + bias[col];
}

// ---------------- flash-decode attention over one S-chunk
__global__ __launch_bounds__(256) void attn_chunk(
    const float* __restrict__ Kp,   // [BB][S_PAST][HH]
    const float* __restrict__ Vp,   // [BB][S_PAST][HH]
    const float* __restrict__ qkv,  // [BB][N_QKV]
    float* __restrict__ part)       // [BB*NHEAD*NCHUNK][PART_STRIDE]
{
    __shared__ __align__(16) float p_lds[SCHUNK];   // 4 KB
    __shared__ __align__(16) float red[8 * HD];     // 4 KB
    __shared__ float sm_scr[8];

    const int tid  = threadIdx.x;
    const int lane = tid & 63;
    const int l32  = tid & 31;
    const int grp  = tid >> 5;          // 0..7 half-wave groups
    const int blk  = blockIdx.x;
    const int c    = blk & 3;
    const int h    = (blk >> 2) & 15;
    const int b    = blk >> 6;

    const float scale = 0.08838834764831845f;  // 1/sqrt(128)

    // q fragment: 4 floats per lane of each 32-group (all groups same)
    const float4* qf = (const float4*)(qkv + (size_t)b * N_QKV + h * HD);
    float4 q4 = qf[l32];
    q4.x *= scale; q4.y *= scale; q4.z *= scale; q4.w *= scale;

    const size_t kvbase = (size_t)b * S_PAST * HH + h * HD;
    const int s0 = c * SCHUNK;

    // ---- phase 1: scores -> p_lds
    const float4* knew = (const float4*)(qkv + (size_t)b * N_QKV + HH + h * HD);
    for (int it = 0; it < SCHUNK / 8; ++it) {
        int s_local = it * 8 + grp;
        int s_g = s0 + s_local;
        const float4* kr = (s_g < S_PAST)
            ? (const float4*)(Kp + kvbase + (size_t)s_g * HH)
            : knew;
        float4 k4 = kr[l32];
        float d = q4.x * k4.x + q4.y * k4.y + q4.z * k4.z + q4.w * k4.w;
        #pragma unroll
        for (int off = 16; off >= 1; off >>= 1)
            d += __shfl_xor(d, off, 64);
        if (l32 == 0) p_lds[s_local] = d;
    }
    __syncthreads();

    // ---- phase 2: chunk-local softmax (unnormalized)
    float4 pv = ((float4*)p_lds)[tid];  // my 4 scores
    float mloc = fmaxf(fmaxf(pv.x, pv.y), fmaxf(pv.z, pv.w));
    #pragma unroll
    for (int off = 32; off >= 1; off >>= 1)
        mloc = fmaxf(mloc, __shfl_xor(mloc, off, 64));
    if (lane == 0) sm_scr[tid >> 6] = mloc;
    __syncthreads();
    float m = fmaxf(fmaxf(sm_scr[0], sm_scr[1]), fmaxf(sm_scr[2], sm_scr[3]));
    float e0 = __expf(pv.x - m);
    float e1 = __expf(pv.y - m);
    float e2 = __expf(pv.z - m);
    float e3 = __expf(pv.w - m);
    ((float4*)p_lds)[tid] = make_float4(e0, e1, e2, e3);
    float sl = e0 + e1 + e2 + e3;
    #pragma unroll
    for (int off = 32; off >= 1; off >>= 1)
        sl += __shfl_xor(sl, off, 64);
    if (lane == 0) sm_scr[4 + (tid >> 6)] = sl;
    __syncthreads();
    float l = sm_scr[4] + sm_scr[5] + sm_scr[6] + sm_scr[7];

    // ---- phase 3: P*V
    float4 acc = make_float4(0.f, 0.f, 0.f, 0.f);
    const float4* vnew = (const float4*)(qkv + (size_t)b * N_QKV + 2 * HH + h * HD);
    for (int it = 0; it < SCHUNK / 8; ++it) {
        int s_local = it * 8 + grp;
        int s_g = s0 + s_local;
        const float4* vr = (s_g < S_PAST)
            ? (const float4*)(Vp + kvbase + (size_t)s_g * HH)
            : vnew;
        float4 v4 = vr[l32];
        float pw = p_lds[s_local];
        acc.x = fmaf(pw, v4.x, acc.x);
        acc.y = fmaf(pw, v4.y, acc.y);
        acc.z = fmaf(pw, v4.z, acc.z);
        acc.w = fmaf(pw, v4.w, acc.w);
    }
    ((float4*)red)[grp * 32 + l32] = acc;
    __syncthreads();

    float* po = part + (size_t)blk * PART_STRIDE;
    if (tid < HD) {
        float s = 0.f;
        #pragma unroll
        for (int g = 0; g < 8; ++g) s += red[g * HD + tid];
        po[tid] = s;
    } else if (tid == HD) {
        po[HD] = m;
    } else if (tid == HD + 1) {
        po[HD + 1] = l;
    }
}

// ---------------- combine chunk partials -> ctx[b][h*HD+d]
__global__ __launch_bounds__(128) void attn_combine(
    const float* __restrict__ part, float* __restrict__ ctx)
{
    int bh = blockIdx.x;   // b*NHEAD + h
    int d  = threadIdx.x;
    const float* p0 = part + (size_t)bh * NCHUNK * PART_STRIDE;
    float m0 = p0[0 * PART_STRIDE + HD];
    float m1 = p0[1 * PART_STRIDE + HD];
    float m2 = p0[2 * PART_STRIDE + HD];
    float m3 = p0[3 * PART_STRIDE + HD];
    float m = fmaxf(fmaxf(m0, m1), fmaxf(m2, m3));
    float w0 = __expf(m0 - m), w1 = __expf(m1 - m);
    float w2 = __expf(m2 - m), w3 = __expf(m3 - m);
    float L = w0 * p0[0 * PART_STRIDE + HD + 1] + w1 * p0[1 * PART_STRIDE + HD + 1]
            + w2 * p0[2 * PART_STRIDE + HD + 1] + w3 * p0[3 * PART_STRIDE + HD + 1];
    float o = w0 * p0[0 * PART_STRIDE + d] + w1 * p0[1 * PART_STRIDE + d]
            + w2 * p0[2 * PART_STRIDE + d] + w3 * p0[3 * PART_STRIDE + d];
    int b = bh >> 4, h = bh & 15;
    ctx[(size_t)b * HH + h * HD + d] = o / L;
}

extern "C" void kernel_launch(void* const* d_in, const int* in_sizes, int n_in,
                              void* d_out, int out_size, void* d_ws, size_t ws_size,
                              hipStream_t stream) {
    const float* x      = (const float*)d_in[0];  // [32][1][2048]
    const float* pkey   = (const float*)d_in[1];  // [32][4095][2048]
    const float* pval   = (const float*)d_in[2];  // [32][4095][2048]
    const float* W_attn = (const float*)d_in[3];  // [2048][6144]
    const float* b_attn = (const float*)d_in[4];  // [6144]
    const float* W_proj = (const float*)d_in[5];  // [2048][2048]
    const float* b_proj = (const float*)d_in[6];  // [2048]
    float* out = (float*)d_out;                   // [32][2048]

    float* ws    = (float*)d_ws;
    float* qkv   = ws;                                   // 196608
    float* qkvp  = qkv + (size_t)BB * N_QKV;             // 8*196608 = 1572864
    float* attnp = qkvp + (size_t)KSPLIT * BB * N_QKV;   // 2048*132 = 270336
    float* ctx   = attnp + (size_t)BB * NHEAD * NCHUNK * PART_STRIDE;  // 65536
    float* projp = ctx + (size_t)BB * HH;                // 8*65536 = 524288

    // 1) qkv partial GEMM
    gemm_xw_partial<<<dim3(N_QKV / 256, KSPLIT), 256, 0, stream>>>(x, W_attn, qkvp, N_QKV);
    // 2) reduce + bias -> qkv
    reduce_bias<<<(BB * N_QKV) / 256, 256, 0, stream>>>(qkvp, b_attn, qkv, N_QKV);
    // 3) flash-decode chunks
    attn_chunk<<<BB * NHEAD * NCHUNK, 256, 0, stream>>>(pkey, pval, qkv, attnp);
    // 4) combine -> ctx
    attn_combine<<<BB * NHEAD, 128, 0, stream>>>(attnp, ctx);
    // 5) out projection partial GEMM
    gemm_xw_partial<<<dim3(HH / 256, KSPLIT), 256, 0, stream>>>(ctx, W_proj, projp, HH);
    // 6) reduce + bias -> out
    reduce_bias<<<(BB * HH) / 256, 256, 0, stream>>>(projp, b_proj, out, HH);
}